// Round 2
// 686.176 us; speedup vs baseline: 1.4610x; 1.4610x over previous
//
#include <hip/hip_runtime.h>
#include <hip/hip_bf16.h>

#define C_DIM 256
#define HW_DIM 16384
#define F_DIM 1024

typedef __hip_bfloat16 bf16;
typedef short short8 __attribute__((ext_vector_type(8)));
typedef float f32x4 __attribute__((ext_vector_type(4)));

__device__ __forceinline__ float bf2f(unsigned short u) {
  unsigned int x = ((unsigned int)u) << 16;
  return __uint_as_float(x);
}
__device__ __forceinline__ unsigned short f2bfbits(float v) {
  bf16 h = __float2bfloat16(v);
  return *(unsigned short*)&h;
}

// ---------------- kernel 0: weight prep ----------------
// Wqkv bf16 [320 r][256 c]: rows 0-31 Wq, 32-63 Wk, 64-319 Wv (row-major).
// W1s: bf16 A-fragments [ft(64)][ks(8)][lane(64)][j(8)]:
//   = W1[f = ft*16 + (lane&15)][k = ks*32 + (lane>>4)*8 + j]
// W2s: bf16 A-fragments [ct(16)][gks(32)][lane(64)][j(8)]:
//   = W2[c = ct*16 + (lane&15)][f = gks*32 + (lane>>4)*8 + j]
__global__ __launch_bounds__(256) void prep_weights(
    const float* __restrict__ Wq, const float* __restrict__ Wk,
    const float* __restrict__ Wv, const float* __restrict__ W1,
    const float* __restrict__ W2, unsigned short* __restrict__ Wqkv,
    unsigned short* __restrict__ W1s, unsigned short* __restrict__ W2s) {
  int i = blockIdx.x * 256 + threadIdx.x;
  if (i < 320 * 256) {
    int r = i >> 8, c = i & 255;
    float v;
    if (r < 32)      v = Wq[r * 256 + c];
    else if (r < 64) v = Wk[(r - 32) * 256 + c];
    else             v = Wv[(r - 64) * 256 + c];
    Wqkv[i] = f2bfbits(v);
  }
  if (i < 32768) {
    int ft = i >> 9, ks = (i >> 6) & 7, l = i & 63;
    int f = ft * 16 + (l & 15), kb = ks * 32 + (l >> 4) * 8;
    #pragma unroll
    for (int j = 0; j < 8; ++j)
      W1s[i * 8 + j] = f2bfbits(W1[f * 256 + kb + j]);
  }
  if (i < 32768) {
    int ct = i >> 11, gks = (i >> 6) & 31, l = i & 63;
    int c = ct * 16 + (l & 15), fb = gks * 32 + (l >> 4) * 8;
    #pragma unroll
    for (int j = 0; j < 8; ++j)
      W2s[i * 8 + j] = f2bfbits(W2[c * 1024 + fb + j]);
  }
}

// ---------------- kernel 1: QKV projection (MFMA, window-major outputs) ----------------
// block = (win, mc): stage Xs[c 256][m 64] bf16; out rows r: 0-31 Q, 32-63 K, 64-319 V.
// Qw/Kw [win][token 256][32] bf16;  Vw [win][c 256][m 256] bf16.
__global__ __launch_bounds__(256) void qkvproj_kernel(
    const float* __restrict__ x, const unsigned short* __restrict__ Wqkv,
    unsigned short* __restrict__ Qw, unsigned short* __restrict__ Kw,
    unsigned short* __restrict__ Vw) {
  __shared__ __align__(16) short Xs[256][68];   // stride 136 B (8B-aligned writes, 2-way-max banks)
  const int bid = blockIdx.x;
  const int win = bid >> 2, mc = bid & 3;
  const int b = win >> 6, wh = (win >> 3) & 7, ww = win & 7;
  const int m0 = mc * 64;
  const int tid = threadIdx.x;
  const int wv = tid >> 6, l = tid & 63;
  const int t = l & 15, q = l >> 4;

  // stage: x[b][c][wh*16 + mc*4 + gh_l][ww*16 + 0..15] -> Xs[c][gh_l*16 + gw]
  #pragma unroll
  for (int rep = 0; rep < 4; ++rep) {
    int seg = rep * 256 + tid;
    int c = seg >> 2, gh_l = seg & 3;
    const float* xp = x + (((size_t)(b * 256 + c) * 128) + wh * 16 + mc * 4 + gh_l) * 128 + ww * 16;
    #pragma unroll
    for (int s = 0; s < 4; ++s) {
      float4 v = *(const float4*)(xp + s * 4);
      ushort4 u;
      u.x = f2bfbits(v.x); u.y = f2bfbits(v.y);
      u.z = f2bfbits(v.z); u.w = f2bfbits(v.w);
      *(ushort4*)&Xs[c][gh_l * 16 + s * 4] = u;
    }
  }
  __syncthreads();

  for (int mt = 0; mt < 4; ++mt) {
    // B-fragments for this m-tile: B[k=c][col=m]
    short8 Bf[8];
    #pragma unroll
    for (int ks = 0; ks < 8; ++ks) {
      short8 bb;
      #pragma unroll
      for (int j = 0; j < 8; ++j)
        bb[j] = Xs[ks * 32 + q * 8 + j][mt * 16 + t];
      Bf[ks] = bb;
    }
    #pragma unroll
    for (int rti = 0; rti < 5; ++rti) {
      const int rt = wv * 5 + rti;
      const int r0 = rt * 16;
      f32x4 acc = (f32x4){0.f, 0.f, 0.f, 0.f};
      #pragma unroll
      for (int ks = 0; ks < 8; ++ks) {
        short8 av = *(const short8*)(Wqkv + (size_t)(r0 + t) * 256 + ks * 32 + q * 8);
        acc = __builtin_amdgcn_mfma_f32_16x16x32_bf16(av, Bf[ks], acc, 0, 0, 0);
      }
      const int n = m0 + mt * 16 + t;   // token (C-layout col)
      if (rt < 4) {
        ushort4 u;
        u.x = f2bfbits(acc[0]); u.y = f2bfbits(acc[1]);
        u.z = f2bfbits(acc[2]); u.w = f2bfbits(acc[3]);
        unsigned short* dst = (rt < 2) ? Qw : Kw;
        int o0 = (rt & 1) * 16 + q * 4;
        *(ushort4*)(dst + ((size_t)win * 256 + n) * 32 + o0) = u;
      } else {
        #pragma unroll
        for (int r = 0; r < 4; ++r) {
          int c = r0 - 64 + q * 4 + r;
          Vw[((size_t)win * 256 + c) * 256 + n] = f2bfbits(acc[r]);
        }
      }
    }
  }
}

// ---------------- kernel 2: fused window attention ----------------
// 1 block/window, 1024 thr = 16 waves (wr=wid>>2, wc=wid&3).
// S = Q K^T -> exp -> Ps (LDS bf16 chunk) -> O^T += V P^T (swapped operands:
// mfma(V_frag, P_frag) so each lane holds 4 CONSECUTIVE CHANNELS at a fixed token).
// Epilogue: direct ushort4 store of XAw[win][m][c] (token-major) — no LDS transpose.
__global__ __launch_bounds__(1024) void attn_fused_kernel(
    const unsigned short* __restrict__ Qw, const unsigned short* __restrict__ Kw,
    const unsigned short* __restrict__ Vw, const float* __restrict__ x,
    const float* __restrict__ gamma, unsigned short* __restrict__ XAw) {
  __shared__ __align__(16) short Ps[256][72];  // 36864 B
  __shared__ float Lpart[4][4][64];
  __shared__ float Ls[256];

  const int win = blockIdx.x;
  const int b = win >> 6, wh = (win >> 3) & 7, ww = win & 7;
  const int tid = threadIdx.x;
  const int wid = tid >> 6, l = tid & 63;
  const int t = l & 15, q = l >> 4;
  const int wr = wid >> 2, wc = wid & 3;

  f32x4 Oacc[4][4];   // [k: c-tile][i: n-tile], D row = c-offset, D col = token
  #pragma unroll
  for (int k = 0; k < 4; ++k)
    #pragma unroll
    for (int i = 0; i < 4; ++i)
      Oacc[k][i] = (f32x4){0.f, 0.f, 0.f, 0.f};
  float lsum[16];
  #pragma unroll
  for (int e = 0; e < 16; ++e) lsum[e] = 0.f;

  const unsigned short* Qb = Qw + (size_t)win * 256 * 32;
  const unsigned short* Kb = Kw + (size_t)win * 256 * 32;
  const unsigned short* Vb = Vw + (size_t)win * 65536;

  // hoist Q fragments (invariant over mcc)
  short8 aq[4];
  #pragma unroll
  for (int i = 0; i < 4; ++i)
    aq[i] = *(const short8*)(Qb + (size_t)((wr * 4 + i) * 16 + t) * 32 + q * 8);

  for (int mcc = 0; mcc < 4; ++mcc) {
    // ---- S chunk: wave (wr,wc): tiles nt = wr*4+i, mt = mcc*4+wc ----
    {
      const int m0s = (mcc * 4 + wc) * 16;
      short8 bk = *(const short8*)(Kb + (size_t)(m0s + t) * 32 + q * 8);
      f32x4 sv[4];
      #pragma unroll
      for (int i = 0; i < 4; ++i)
        sv[i] = __builtin_amdgcn_mfma_f32_16x16x32_bf16(aq[i], bk, (f32x4){0.f,0.f,0.f,0.f}, 0, 0, 0);
      #pragma unroll
      for (int i = 0; i < 4; ++i) {
        #pragma unroll
        for (int r = 0; r < 4; ++r) {
          float e = __expf(sv[i][r]);
          lsum[i * 4 + r] += e;
          Ps[(wr * 4 + i) * 16 + q * 4 + r][wc * 16 + t] = (short)f2bfbits(e);
        }
      }
    }
    __syncthreads();
    // ---- PV chunk (swapped): O^T[c][n] += V[c, chunk] @ P^T[chunk, n] ----
    #pragma unroll
    for (int ks2 = 0; ks2 < 2; ++ks2) {
      short8 ap[4], bv[4];
      #pragma unroll
      for (int i = 0; i < 4; ++i)
        ap[i] = *(const short8*)&Ps[(wr * 4 + i) * 16 + t][ks2 * 32 + q * 8];
      #pragma unroll
      for (int k = 0; k < 4; ++k)
        bv[k] = *(const short8*)(Vb + (size_t)((wc * 4 + k) * 16 + t) * 256 + mcc * 64 + ks2 * 32 + q * 8);
      #pragma unroll
      for (int k = 0; k < 4; ++k)
        #pragma unroll
        for (int i = 0; i < 4; ++i)
          Oacc[k][i] = __builtin_amdgcn_mfma_f32_16x16x32_bf16(bv[k], ap[i], Oacc[k][i], 0, 0, 0);
    }
    __syncthreads();
  }

  // ---- row sums: reduce over the 16 col-lanes, combine across wc ----
  #pragma unroll
  for (int mask = 1; mask < 16; mask <<= 1)
    #pragma unroll
    for (int e = 0; e < 16; ++e)
      lsum[e] += __shfl_xor(lsum[e], mask);
  if (t == 0) {
    #pragma unroll
    for (int i = 0; i < 4; ++i)
      *(float4*)&Lpart[wr][wc][i * 16 + q * 4] =
          make_float4(lsum[i * 4 + 0], lsum[i * 4 + 1], lsum[i * 4 + 2], lsum[i * 4 + 3]);
  }
  __syncthreads();
  if (tid < 256) {
    int wrr = tid >> 6, nl = tid & 63;
    float s = Lpart[wrr][0][nl] + Lpart[wrr][1][nl] + Lpart[wrr][2][nl] + Lpart[wrr][3][nl];
    Ls[tid] = gamma[0] / s;
  }
  __syncthreads();

  // ---- epilogue: per lane, token n = (wr*4+i)*16 + t, channels cb..cb+3 contiguous ----
  const float* xb = x + (size_t)b * 256 * 16384 + ((size_t)(wh * 16 + wr * 4)) * 128 + ww * 16 + t;
  #pragma unroll
  for (int i = 0; i < 4; ++i) {
    const int n = (wr * 4 + i) * 16 + t;
    const float ls = Ls[n];
    unsigned short* dst = XAw + ((size_t)win * 256 + n) * 256;
    #pragma unroll
    for (int k = 0; k < 4; ++k) {
      const int cb = (wc * 4 + k) * 16 + q * 4;
      ushort4 u;
      unsigned short* up = (unsigned short*)&u;
      #pragma unroll
      for (int r = 0; r < 4; ++r) {
        float xa = xb[(size_t)(cb + r) * 16384 + i * 128];
        float o = ls * Oacc[k][i][r] + xa;
        up[r] = f2bfbits(o);
      }
      *(ushort4*)(dst + cb) = u;
    }
  }
}

// ---------------- kernel 3: fused MFMA FFN + both LayerNorms ----------------
// block = (win, mc): 64 pixels. Reads token-major XAw[win][m][c] bf16 (contiguous
// staging, no transpose, no bank conflicts), bias/LN vectors as float4 global loads.
// Ht single-buffer [64][136] (128 f-values per fc chunk + pad). LDS 53248 B -> 3 blocks/CU.
__global__ __launch_bounds__(256, 3) void ffn_mfma_kernel(
    const unsigned short* __restrict__ XAw,
    const unsigned short* __restrict__ W1s, const unsigned short* __restrict__ W2s,
    const float* __restrict__ b1, const float* __restrict__ b2,
    const float* __restrict__ ln1w, const float* __restrict__ ln1b,
    const float* __restrict__ ln2w, const float* __restrict__ ln2b,
    float* __restrict__ out) {
  __shared__ __align__(16) short Xt[64][264];     // 33792 B, stride 528 B
  __shared__ __align__(16) short Ht[64][136];     // 17408 B, stride 272 B (holds 128 f + pad)
  __shared__ float red[2][4][64];                 // 2048 B; [*][0][*] reused for mu/rs

  const int bid = blockIdx.x;
  const int win = bid >> 2, mc = bid & 3;
  const int b = win >> 6, wh = (win >> 3) & 7, ww = win & 7;
  const int tid = threadIdx.x;
  const int wv = tid >> 6, l = tid & 63;
  const int p = l & 15, q = l >> 4;
  const unsigned short* XWb = XAw + ((size_t)win * 256 + mc * 64) * 256;  // [m][c]

  // stage X tile: straight vectorized copy (16 B loads + 16 B LDS writes)
  #pragma unroll
  for (int rep = 0; rep < 8; ++rep) {
    int s = rep * 256 + tid;
    int row = s >> 5, col8 = (s & 31) * 8;
    short8 v = *(const short8*)(XWb + (size_t)row * 256 + col8);
    *(short8*)&Xt[row][col8] = v;
  }
  __syncthreads();

  f32x4 Yacc[4][4];
  #pragma unroll
  for (int i = 0; i < 4; ++i)
    #pragma unroll
    for (int pt = 0; pt < 4; ++pt)
      Yacc[i][pt] = (f32x4){0.f, 0.f, 0.f, 0.f};

  const short8* W1s8 = (const short8*)W1s;
  const short8* W2s8 = (const short8*)W2s;

  for (int fc = 0; fc < 8; ++fc) {
    f32x4 Hacc[2][4];
    #pragma unroll
    for (int i = 0; i < 2; ++i)
      #pragma unroll
      for (int pt = 0; pt < 4; ++pt)
        Hacc[i][pt] = (f32x4){0.f, 0.f, 0.f, 0.f};
    const int f0 = (fc * 8 + wv * 2) * 8;
    #pragma unroll
    for (int ks = 0; ks < 8; ++ks) {
      short8 a0 = W1s8[(f0 + ks) * 64 + l];
      short8 a1 = W1s8[(f0 + 8 + ks) * 64 + l];
      #pragma unroll
      for (int pt = 0; pt < 4; ++pt) {
        short8 bf = *(const short8*)&Xt[pt * 16 + p][ks * 32 + q * 8];
        Hacc[0][pt] = __builtin_amdgcn_mfma_f32_16x16x32_bf16(a0, bf, Hacc[0][pt], 0, 0, 0);
        Hacc[1][pt] = __builtin_amdgcn_mfma_f32_16x16x32_bf16(a1, bf, Hacc[1][pt], 0, 0, 0);
      }
    }
    __syncthreads();   // all waves finished reading Ht (previous fc's Y-GEMM)
    // bias + GELU -> Ht
    #pragma unroll
    for (int i = 0; i < 2; ++i) {
      float4 bv1 = *(const float4*)(b1 + fc * 128 + wv * 32 + i * 16 + q * 4);
      #pragma unroll
      for (int pt = 0; pt < 4; ++pt) {
        ushort4 hbv;
        unsigned short* hp = (unsigned short*)&hbv;
        #pragma unroll
        for (int r = 0; r < 4; ++r) {
          float v = Hacc[i][pt][r] + ((const float*)&bv1)[r];
          float u = 0.7978845608f * fmaf(0.044715f * v, v * v, v);
          float e = __expf(2.f * u);
          float g = v - v / (e + 1.f);
          hp[r] = f2bfbits(g);
        }
        *(ushort4*)&Ht[pt * 16 + p][wv * 32 + i * 16 + q * 4] = hbv;
      }
    }
    __syncthreads();   // Ht ready
    #pragma unroll
    for (int fs = 0; fs < 4; ++fs) {
      short8 av[4];
      #pragma unroll
      for (int i = 0; i < 4; ++i)
        av[i] = W2s8[((wv * 4 + i) * 32 + fc * 4 + fs) * 64 + l];
      #pragma unroll
      for (int pt = 0; pt < 4; ++pt) {
        short8 bf = *(const short8*)&Ht[pt * 16 + p][fs * 32 + q * 8];
        #pragma unroll
        for (int i = 0; i < 4; ++i)
          Yacc[i][pt] = __builtin_amdgcn_mfma_f32_16x16x32_bf16(av[i], bf, Yacc[i][pt], 0, 0, 0);
      }
    }
  }

  // bias b2
  #pragma unroll
  for (int i = 0; i < 4; ++i) {
    float4 bb = *(const float4*)(b2 + wv * 64 + i * 16 + q * 4);
    #pragma unroll
    for (int pt = 0; pt < 4; ++pt)
      #pragma unroll
      for (int r = 0; r < 4; ++r)
        Yacc[i][pt][r] += ((const float*)&bb)[r];
  }

  // LN1 stats
  #pragma unroll
  for (int pt = 0; pt < 4; ++pt) {
    float ss = 0.f, sq = 0.f;
    #pragma unroll
    for (int i = 0; i < 4; ++i)
      #pragma unroll
      for (int r = 0; r < 4; ++r) { float v = Yacc[i][pt][r]; ss += v; sq += v * v; }
    ss += __shfl_xor(ss, 16); sq += __shfl_xor(sq, 16);
    ss += __shfl_xor(ss, 32); sq += __shfl_xor(sq, 32);
    if (l < 16) { red[0][wv][pt * 16 + l] = ss; red[1][wv][pt * 16 + l] = sq; }
  }
  __syncthreads();
  if (tid < 64) {
    float S  = red[0][0][tid] + red[0][1][tid] + red[0][2][tid] + red[0][3][tid];
    float Q2 = red[1][0][tid] + red[1][1][tid] + red[1][2][tid] + red[1][3][tid];
    float m = S * 0.00390625f;
    float va = Q2 * 0.00390625f - m * m;
    red[0][0][tid] = m; red[1][0][tid] = rsqrtf(va + 1e-5f);
  }
  __syncthreads();
  // x2 = xa + LN1(y); xa re-read from LDS (Xt), not global
  #pragma unroll
  for (int i = 0; i < 4; ++i) {
    float4 w1v = *(const float4*)(ln1w + wv * 64 + i * 16 + q * 4);
    float4 b1v = *(const float4*)(ln1b + wv * 64 + i * 16 + q * 4);
    #pragma unroll
    for (int pt = 0; pt < 4; ++pt) {
      int px = pt * 16 + p;
      float mu = red[0][0][px], rs = red[1][0][px];
      #pragma unroll
      for (int r = 0; r < 4; ++r) {
        int c = wv * 64 + i * 16 + q * 4 + r;
        float xa = bf2f((unsigned short)Xt[px][c]);
        Yacc[i][pt][r] = xa + (Yacc[i][pt][r] - mu) * rs * ((const float*)&w1v)[r] + ((const float*)&b1v)[r];
      }
    }
  }
  __syncthreads();   // protect red[*][0][*] before stats-2 overwrites
  // LN2 stats
  #pragma unroll
  for (int pt = 0; pt < 4; ++pt) {
    float ss = 0.f, sq = 0.f;
    #pragma unroll
    for (int i = 0; i < 4; ++i)
      #pragma unroll
      for (int r = 0; r < 4; ++r) { float v = Yacc[i][pt][r]; ss += v; sq += v * v; }
    ss += __shfl_xor(ss, 16); sq += __shfl_xor(sq, 16);
    ss += __shfl_xor(ss, 32); sq += __shfl_xor(sq, 32);
    if (l < 16) { red[0][wv][pt * 16 + l] = ss; red[1][wv][pt * 16 + l] = sq; }
  }
  __syncthreads();
  if (tid < 64) {
    float S  = red[0][0][tid] + red[0][1][tid] + red[0][2][tid] + red[0][3][tid];
    float Q2 = red[1][0][tid] + red[1][1][tid] + red[1][2][tid] + red[1][3][tid];
    float m = S * 0.00390625f;
    float va = Q2 * 0.00390625f - m * m;
    red[0][0][tid] = m; red[1][0][tid] = rsqrtf(va + 1e-5f);
  }
  __syncthreads();
  // out = x2 + LN2(x2), NCHW
  #pragma unroll
  for (int i = 0; i < 4; ++i) {
    float4 w2v = *(const float4*)(ln2w + wv * 64 + i * 16 + q * 4);
    float4 b2v = *(const float4*)(ln2b + wv * 64 + i * 16 + q * 4);
    #pragma unroll
    for (int pt = 0; pt < 4; ++pt) {
      int px = pt * 16 + p;
      float mu = red[0][0][px], rs = red[1][0][px];
      #pragma unroll
      for (int r = 0; r < 4; ++r) {
        int c = wv * 64 + i * 16 + q * 4 + r;
        float x2 = Yacc[i][pt][r];
        float o = x2 + (x2 - mu) * rs * ((const float*)&w2v)[r] + ((const float*)&b2v)[r];
        out[(((size_t)(b * 256 + c) * 128) + wh * 16 + mc * 4 + pt) * 128 + ww * 16 + p] = o;
      }
    }
  }
}

extern "C" void kernel_launch(void* const* d_in, const int* in_sizes, int n_in,
                              void* d_out, int out_size, void* d_ws, size_t ws_size,
                              hipStream_t stream) {
  const float* x     = (const float*)d_in[0];
  const float* Wq    = (const float*)d_in[1];
  const float* Wk    = (const float*)d_in[2];
  const float* Wv    = (const float*)d_in[3];
  const float* gamma = (const float*)d_in[4];
  const float* W1    = (const float*)d_in[5];
  const float* b1    = (const float*)d_in[6];
  const float* W2    = (const float*)d_in[7];
  const float* b2    = (const float*)d_in[8];
  const float* ln1w  = (const float*)d_in[9];
  const float* ln1b  = (const float*)d_in[10];
  const float* ln2w  = (const float*)d_in[11];
  const float* ln2b  = (const float*)d_in[12];
  float* out = (float*)d_out;

  char* wsb = (char*)d_ws;
  unsigned short* XAw  = (unsigned short*)wsb;                 // 33554432 bf16 = 67108864 B, token-major [win][m][c]
  unsigned short* Vw   = (unsigned short*)(wsb + 67108864);    // 33554432 bf16
  unsigned short* Qw   = (unsigned short*)(wsb + 134217728);   // 4194304 bf16
  unsigned short* Kw   = (unsigned short*)(wsb + 142606336);   // 4194304 bf16
  unsigned short* Wqkv = (unsigned short*)(wsb + 150994944);   // 81920 bf16
  unsigned short* W1s  = (unsigned short*)(wsb + 151158784);   // 262144 bf16
  unsigned short* W2s  = (unsigned short*)(wsb + 151683072);   // 262144 bf16 -> end ~145 MB

  prep_weights<<<1024, 256, 0, stream>>>(Wq, Wk, Wv, W1, W2, Wqkv, W1s, W2s);
  qkvproj_kernel<<<2048, 256, 0, stream>>>(x, Wqkv, Qw, Kw, Vw);
  attn_fused_kernel<<<512, 1024, 0, stream>>>(Qw, Kw, Vw, x, gamma, XAw);
  ffn_mfma_kernel<<<2048, 256, 0, stream>>>(XAw, W1s, W2s, b1, b2, ln1w, ln1b, ln2w, ln2b, out);
}